// Round 5
// baseline (327.729 us; speedup 1.0000x reference)
//
#include <hip/hip_runtime.h>
#include <hip/hip_bf16.h>

#define BATCH 4096
#define DK    2048
#define NCOMP 8
#define NC    8192
#define NT    (DK / 64)

typedef unsigned int u32;
typedef unsigned short u16;
typedef short bf16x8 __attribute__((ext_vector_type(8)));
typedef float f32x4 __attribute__((ext_vector_type(4)));
#define AS1 __attribute__((address_space(1)))
#define AS3 __attribute__((address_space(3)))

__device__ __forceinline__ u16 f2bf(float f) {
    union { float f; u32 u; } v; v.f = f;
    u32 r = v.u + 0x7fffu + ((v.u >> 16) & 1u);  // RNE
    return (u16)(r >> 16);
}

// ---------------- W cast: one float4 -> ushort4 per thread, fully coalesced ----------------
__global__ void cvtW_kernel(const float* __restrict__ in, u16* __restrict__ out) {
    int i = blockIdx.x * blockDim.x + threadIdx.x;
    float4 a = ((const float4*)in)[i];
    ushort4 o = { f2bf(a.x), f2bf(a.y), f2bf(a.z), f2bf(a.w) };
    ((ushort4*)out)[i] = o;
}

// ---------------- fused x cast + gate: one block per row, x read ONCE ----------------
__global__ __launch_bounds__(256)
void xgate_kernel(const float* __restrict__ x, const float* __restrict__ wg,
                  const float* __restrict__ wgb, u16* __restrict__ xb,
                  float* __restrict__ G) {
    int row = blockIdx.x;
    int t = threadIdx.x;
    const float4* xr = (const float4*)(x + (size_t)row * DK);
    const float4* wr = (const float4*)wg;
    float4 a = xr[t], b = xr[t + 256];
    float4 wa = wr[t], wb = wr[t + 256];
    float s = a.x*wa.x + a.y*wa.y + a.z*wa.z + a.w*wa.w
            + b.x*wb.x + b.y*wb.y + b.z*wb.z + b.w*wb.w;
    ushort4 o1 = { f2bf(a.x), f2bf(a.y), f2bf(a.z), f2bf(a.w) };
    ushort4 o2 = { f2bf(b.x), f2bf(b.y), f2bf(b.z), f2bf(b.w) };
    ushort4* xo = (ushort4*)(xb + (size_t)row * DK);
    xo[t] = o1;
    xo[t + 256] = o2;
    __shared__ float red[4];
#pragma unroll
    for (int off = 32; off; off >>= 1) s += __shfl_xor(s, off, 64);
    if ((t & 63) == 0) red[t >> 6] = s;
    __syncthreads();
    if (t == 0) {
        float sum = (red[0] + red[1]) + (red[2] + red[3]);
        float g = 0.5f * (float)NCOMP * (1.0f + tanhf(sum + wgb[0]));
        float k = floorf(g);
        float mh[NCOMP]; float den = 0.f;
#pragma unroll
        for (int n = 0; n < NCOMP; ++n) {
            float m = ((float)n <= k) ? 1.0f : 0.0f;
            m = (m - g) + g;            // replicate straight-through forward rounding
            mh[n] = m; den += fabsf(m);
        }
        den = fmaxf(den, 1e-12f);
#pragma unroll
        for (int n = 0; n < NCOMP; ++n) G[(size_t)row * NCOMP + n] = mh[n] / den;
    }
}

// ---------------- 256x256 bf16 MFMA GEMM, 4-window pipelined schedule ----------------
// LDS half-tile: [128 rows][8 slots of 16B]; (row,slot) holds global (row, slot^(row&7)).
// Buffer u16 offsets: buf*32768; regions A0=0, A1=8192, B0=16384, B1=24576.
// Steady-state per tile: W0 stages (t+1).A1, W2 stages (t+2).B0, W3 stages (t+2).{B1,A0};
// vmcnt(2) at W3 retires through (t+1).A1 (leaves (t+2).B0 in flight); barrier; then the
// next tile's aF is read (safe: all waves' vmcnt passed). lgkm waits are counted so each
// read group retires under an MFMA window: bG rides W0, aG rides W1, next-aF rides W3.

#define BAR()        __builtin_amdgcn_s_barrier()
#define SCHED0()     __builtin_amdgcn_sched_barrier(0)
#define PRIO(N)      __builtin_amdgcn_s_setprio(N)
#define WAIT_LGKM(N) asm volatile("s_waitcnt lgkmcnt(" #N ")" ::: "memory")
#define WAIT_VM(N)   asm volatile("s_waitcnt vmcnt(" #N ")" ::: "memory")

// 2 x global_load_lds(16B) covering one 128x64 half-tile across 512 threads.
#define STAGE(usrc, dhalf) do { \
    __builtin_amdgcn_global_load_lds((const AS1 u32*)((usrc) + go0), (AS3 u32*)((dhalf) + d0), 16, 0, 0); \
    __builtin_amdgcn_global_load_lds((const AS1 u32*)((usrc) + go1), (AS3 u32*)((dhalf) + d1), 16, 0, 0); \
  } while (0)

#define MFQ(MB, NB, AFR, BFR) \
  do { _Pragma("unroll") for (int j = 0; j < 4; ++j) \
       _Pragma("unroll") for (int jn = 0; jn < 2; ++jn) \
       _Pragma("unroll") for (int kk = 0; kk < 2; ++kk) \
         acc[(MB) + j][(NB) + jn] = __builtin_amdgcn_mfma_f32_16x16x32_bf16( \
             AFR[j][kk], BFR[jn][kk], acc[(MB) + j][(NB) + jn], 0, 0, 0); } while (0)

// MODE 0 = steady, 1 = penultimate (only A1 stage), 2 = last (no stages, no next-aF)
template<int MODE>
__device__ __forceinline__ void tile_body(
    const u16* Ab0, const u16* Ab1, const u16* Bb0, const u16* Bb1,
    const u16* nAb0, const u16* nAb1,
    const u16* uA1n, const u16* uB0, const u16* uB1, const u16* uA0,
    u16* dA1n, u16* dB0, u16* dB1, u16* dA0,
    u32 go0, u32 go1, int d0, int d1,
    bf16x8 (&aF)[4][2], bf16x8 (&aG)[4][2], bf16x8 (&bF)[2][2], bf16x8 (&bG)[2][2],
    f32x4 (&acc)[8][4])
{
    // ---- W0: stage (t+1).A1; issue bF then bG; MFMA q(0,0) after lgkm(4) [leaves bG]
    if (MODE <= 1) STAGE(uA1n, dA1n);
#pragma unroll
    for (int jn = 0; jn < 2; ++jn) {
        bF[jn][0] = *(const bf16x8*)(Bb0 + jn * 1024);
        bF[jn][1] = *(const bf16x8*)(Bb1 + jn * 1024);
    }
    SCHED0();
#pragma unroll
    for (int jn = 0; jn < 2; ++jn) {
        bG[jn][0] = *(const bf16x8*)(Bb0 + 2048 + jn * 1024);
        bG[jn][1] = *(const bf16x8*)(Bb1 + 2048 + jn * 1024);
    }
    BAR();
    WAIT_LGKM(4);
    SCHED0(); PRIO(1);
    MFQ(0, 0, aF, bF);
    PRIO(0); BAR();

    // ---- W1: issue aG; MFMA q(0,1) after lgkm(8) [retires bG, leaves aG]
#pragma unroll
    for (int j = 0; j < 4; ++j) {
        aG[j][0] = *(const bf16x8*)(Ab0 + 4096 + j * 1024);
        aG[j][1] = *(const bf16x8*)(Ab1 + 4096 + j * 1024);
    }
    BAR();
    WAIT_LGKM(8);
    SCHED0(); PRIO(1);
    MFQ(0, 2, aF, bG);
    PRIO(0); BAR();

    // ---- W2: stage (t+2).B0; MFMA q(1,1) after lgkm(0) [drains aG]
    if (MODE == 0) STAGE(uB0, dB0);
    BAR();
    WAIT_LGKM(0);
    SCHED0(); PRIO(1);
    MFQ(4, 2, aG, bG);
    PRIO(0); BAR();

    // ---- W3: counted vmcnt; stage (t+2).{B1,A0}; BARRIER; then read next aF; MFMA q(1,0)
    if (MODE == 0) {
        WAIT_VM(2);              // (t+1) halves all landed; (t+2).B0 stays in flight
        STAGE(uB1, dB1);
        STAGE(uA0, dA0);
    } else if (MODE == 1) {
        WAIT_VM(0);
    }
    BAR();                        // all waves' vmcnt passed -> (t+1) buffer fully visible
    if (MODE != 2) {
#pragma unroll
        for (int j = 0; j < 4; ++j) {
            aF[j][0] = *(const bf16x8*)(nAb0 + j * 1024);
            aF[j][1] = *(const bf16x8*)(nAb1 + j * 1024);
        }
        WAIT_LGKM(8);             // leaves aF in flight (drained at next W0)
    } else {
        WAIT_LGKM(0);
    }
    SCHED0(); PRIO(1);
    MFQ(4, 0, aG, bF);
    PRIO(0);
    if (MODE != 2) BAR();
}

__global__ __launch_bounds__(512, 2)
void gemm_kernel(const u16* __restrict__ A, const u16* __restrict__ Bw,
                 const float* __restrict__ bias, const float* __restrict__ Gtab,
                 float* __restrict__ E) {
    __shared__ u16 lds[2 * 32768];           // 128 KiB
    int tid = threadIdx.x;
    int l = tid & 63;
    int w = tid >> 6;
    int wr = w >> 2, wc = w & 3;             // 2 x 4 waves
    int wcB = wc >> 1, brB = (wc & 1) * 64;
    int r16 = l & 15, kg = l >> 4;

    int bid = blockIdx.x;
    int swz = (bid & 7) * 64 + (bid >> 3);   // 512 blocks, bijective XCD swizzle
    int brow = (swz >> 5) * 256;
    int bcol = (swz & 31) * 256;

    f32x4 acc[8][4] = {};
    bf16x8 aF[4][2], aG[4][2], bF[2][2], bG[2][2];

    const u16* gA = A + (size_t)brow * DK;
    const u16* gB = Bw + (size_t)bcol * DK;

    // per-thread stage voffsets (invariant)
    int c1 = tid + 512;
    u32 go0 = (u32)((tid >> 3) * DK + (((tid & 7) ^ ((tid >> 3) & 7)) * 8));
    u32 go1 = (u32)((c1 >> 3) * DK + (((c1 & 7) ^ ((c1 >> 3) & 7)) * 8));
    int d0 = w * 512, d1 = w * 512 + 4096;   // wave-uniform LDS dst offsets

    // per-thread fragment base pointers (invariant; imm offsets do the rest)
    int swb = r16 * 64;
    int sw0 = ((kg) ^ (r16 & 7)) * 8;
    int sw1 = ((4 + kg) ^ (r16 & 7)) * 8;
    const u16* Ab0_ = lds + wr * 8192 + swb + sw0;
    const u16* Ab1_ = lds + wr * 8192 + swb + sw1;
    const u16* Bb0_ = lds + 16384 + wcB * 8192 + brB * 64 + swb + sw0;
    const u16* Bb1_ = lds + 16384 + wcB * 8192 + brB * 64 + swb + sw1;

    // prologue: t0 fully + t1.{B0,B1,A0}; t1.A1 staged in t0's W0
    STAGE(gA,                 lds);
    STAGE(gA + 128 * DK,      lds + 8192);
    STAGE(gB,                 lds + 16384);
    STAGE(gB + 128 * DK,      lds + 24576);
    STAGE(gB + 64,            lds + 32768 + 16384);
    STAGE(gB + 128 * DK + 64, lds + 32768 + 24576);
    STAGE(gA + 64,            lds + 32768);
    WAIT_VM(6);                              // t0's 8 loads retired
    BAR();
#pragma unroll
    for (int j = 0; j < 4; ++j) {            // t0's aF, left in flight into W0
        aF[j][0] = *(const bf16x8*)(Ab0_ + j * 1024);
        aF[j][1] = *(const bf16x8*)(Ab1_ + j * 1024);
    }

#pragma unroll 1
    for (int t = 0; t <= NT - 3; ++t) {
        u32 cbo = (u32)(t & 1) * 32768, nbo = cbo ^ 32768;
        tile_body<0>(Ab0_ + cbo, Ab1_ + cbo, Bb0_ + cbo, Bb1_ + cbo,
                     Ab0_ + nbo, Ab1_ + nbo,
                     gA + 128 * DK + (size_t)(t + 1) * 64,
                     gB + (size_t)(t + 2) * 64,
                     gB + 128 * DK + (size_t)(t + 2) * 64,
                     gA + (size_t)(t + 2) * 64,
                     lds + nbo + 8192, lds + cbo + 16384, lds + cbo + 24576, lds + cbo,
                     go0, go1, d0, d1, aF, aG, bF, bG, acc);
    }
    {
        int t = NT - 2;
        u32 cbo = (u32)(t & 1) * 32768, nbo = cbo ^ 32768;
        tile_body<1>(Ab0_ + cbo, Ab1_ + cbo, Bb0_ + cbo, Bb1_ + cbo,
                     Ab0_ + nbo, Ab1_ + nbo,
                     gA + 128 * DK + (size_t)(t + 1) * 64, gB, gB, gA,
                     lds + nbo + 8192, lds + cbo + 16384, lds + cbo + 24576, lds + cbo,
                     go0, go1, d0, d1, aF, aG, bF, bG, acc);
    }
    {
        int t = NT - 1;
        u32 cbo = (u32)(t & 1) * 32768, nbo = cbo ^ 32768;
        tile_body<2>(Ab0_ + cbo, Ab1_ + cbo, Bb0_ + cbo, Bb1_ + cbo,
                     Ab0_ + nbo, Ab1_ + nbo,
                     gA, gB, gB, gA,
                     lds + nbo + 8192, lds + cbo + 16384, lds + cbo + 24576, lds + cbo,
                     go0, go1, d0, d1, aF, aG, bF, bG, acc);
    }

    // epilogue: E = G[row, n] * (acc + bias[col]); n uniform per wave
    int ncomp = (bcol + wc * 64) >> 10;
    int rbase = brow + wr * 128;
    int cbase = bcol + wc * 64;
    float bs[4];
#pragma unroll
    for (int ni = 0; ni < 4; ++ni) bs[ni] = bias[cbase + ni * 16 + r16];
#pragma unroll
    for (int mi = 0; mi < 8; ++mi)
#pragma unroll
        for (int r = 0; r < 4; ++r) {
            int row = rbase + mi * 16 + kg * 4 + r;
            float gv = Gtab[(size_t)row * NCOMP + ncomp];
            float* Erow = E + (size_t)row * NC + cbase;
#pragma unroll
            for (int ni = 0; ni < 4; ++ni)
                Erow[ni * 16 + r16] = gv * (acc[mi][ni][r] + bs[ni]);
        }
}

extern "C" void kernel_launch(void* const* d_in, const int* in_sizes, int n_in,
                              void* d_out, int out_size, void* d_ws, size_t ws_size,
                              hipStream_t stream) {
    const float* x   = (const float*)d_in[0];
    const float* W   = (const float*)d_in[1];
    const float* b   = (const float*)d_in[2];
    const float* wgw = (const float*)d_in[3];
    const float* wgb = (const float*)d_in[4];
    float* E = (float*)d_out;
    float* G = E + (size_t)BATCH * NC;

    u16* xb = (u16*)d_ws;                      // 16 MiB
    u16* Wb = xb + (size_t)BATCH * DK;         // 32 MiB

    cvtW_kernel<<<NC * DK / 4 / 256, 256, 0, stream>>>(W, Wb);
    xgate_kernel<<<BATCH, 256, 0, stream>>>(x, wgw, wgb, xb, G);
    gemm_kernel<<<(BATCH / 256) * (NC / 256), 512, 0, stream>>>(xb, Wb, b, G, E);
}